// Round 6
// baseline (274.376 us; speedup 1.0000x reference)
//
#include <hip/hip_runtime.h>

typedef unsigned int u32;
typedef unsigned short u16;
typedef short s16x8 __attribute__((ext_vector_type(8)));
typedef u16 u16x8 __attribute__((ext_vector_type(8)));
typedef float f32x4 __attribute__((ext_vector_type(4)));
typedef __attribute__((address_space(3))) u32 as3_u32;
typedef __attribute__((address_space(1))) const u32 as1_u32;

constexpr int MM = 16384, NN = 3072, KK = 1024;
constexpr int BM = 256, BN = 256, BK = 64;
constexpr int NT = KK / BK;  // 16 K-tiles

template <int V> struct IC { static constexpr int value = V; };

__device__ __forceinline__ u16 f2bf(float f) {
  u32 u = __builtin_bit_cast(u32, f);
  u = (u + 0x7FFFu + ((u >> 16) & 1u)) >> 16;
  return (u16)u;
}

__device__ __forceinline__ void gload_lds16(const void* g, void* l) {
  __builtin_amdgcn_global_load_lds((as1_u32*)g, (as3_u32*)l, 16, 0, 0);
}

// ---------- merged prep: blocks [0,12288) fold weights, [12288,20480) cvt x ----------
constexpr int WEFF_BLOCKS = NN * KK / 256;            // 12288
constexpr int CVT_BLOCKS = MM * KK / 8 / 256;         // 8192
__global__ __launch_bounds__(256) void prep(
    const float* __restrict__ w, const float* __restrict__ aq,
    const float* __restrict__ bq, const float* __restrict__ av,
    const float* __restrict__ bv, u16* __restrict__ weff,
    const float* __restrict__ x, u16* __restrict__ xb) {
  const int bid = blockIdx.x;
  if (bid < WEFF_BLOCKS) {
    int idx = bid * 256 + threadIdx.x;
    int o = idx >> 10, d = idx & 1023;
    float val = w[idx];
    if (o < 1024) {
      float s = 0.f;
#pragma unroll
      for (int r = 0; r < 16; ++r) s += bq[o * 16 + r] * aq[r * 1024 + d];
      val += s * 0.0625f;                              // SCALING = 1/16
    } else if (o >= 2048) {
      int o2 = o - 2048;
      float s = 0.f;
#pragma unroll
      for (int r = 0; r < 16; ++r) s += bv[o2 * 16 + r] * av[r * 1024 + d];
      val += s * 0.0625f;
    }
    weff[idx] = f2bf(val);
  } else {
    size_t i = ((size_t)(bid - WEFF_BLOCKS) * 256 + threadIdx.x) * 8;
    float4 f0 = *(const float4*)(x + i);
    float4 f1 = *(const float4*)(x + i + 4);
    u16x8 o;
    o[0] = f2bf(f0.x); o[1] = f2bf(f0.y); o[2] = f2bf(f0.z); o[3] = f2bf(f0.w);
    o[4] = f2bf(f1.x); o[5] = f2bf(f1.y); o[6] = f2bf(f1.z); o[7] = f2bf(f1.w);
    *(u16x8*)(xb + i) = o;
  }
}

// ---------- 256x256 GEMM, derived-wait 4-phase pipeline (race-fixed) ----------
// vmcnt is PER-WAVE: any LDS read of other waves' staged chunks must sit
// after a BARRIER that follows all waves' vmcnt gate (R5 bug: readahead was
// gate-but-not-barrier protected). Two gates per tile, each before a BAR:
//  P1: [bh; STAGE A0(t+1)]    BAR lgkm(4) MFMA(0,0) vmcnt(G1)          BAR
//  P2: [a1; STAGE A1(t+1)]    BAR lgkm(8) MFMA(0,1)                    BAR
//  P3: [STAGE B0(t+2)]        BAR lgkm(0) MFMA(1,1) vmcnt(G2)          BAR
//  P4: [STAGE B1(t+2); MFMA(1,0); readahead a0,bl(t+1)]                BAR
// vm queue (2 loads per STAGE, oldest first), steady state:
//  @G1 post-stage: [A1(t),B0(t+1),B1(t+1),A0(t+1)] = 8 -> vmcnt(6) drains
//    A1(t) (read by P2's LDA after the BAR).
//  @G2 post-stage: [B0(t+1),B1(t+1),A0(t+1),A1(t+1),B0(t+2)] = 10 ->
//    vmcnt(4) drains B(t+1)+A0(t+1) (read by P4's readahead after the BAR).
// Tail: t=14 G1=6,G2=2; t=15 G1=0, no G2/readahead.
// lgkm (in-order DS): P1 lgkm(4): RA(12)+bh(4) -> RA done. P2 lgkm(8):
//  bh+a1(8) -> bh done. P3 lgkm(0): a1 done. P4 MFMA needs a1,bl: done.
// Stage WAR: A0->sA[cb^1]h0 readers drained t-1 P1 lgkm(4); A1->h1 drained
//  t-1 P3 lgkm(0); B0->sB[cb]h0 readers (bl P1 lgkm(4), bh P2 lgkm(8));
//  B1->h1 same. Readahead targets next overwritten >=2 tiles later.
__global__ __launch_bounds__(512, 2) void gemm8p(
    const u16* __restrict__ Ag, const u16* __restrict__ Bg,
    const float* __restrict__ bias, float* __restrict__ C) {
  __shared__ __align__(16) u16 sA[2][BM * BK];  // 64 KB
  __shared__ __align__(16) u16 sB[2][BN * BK];  // 64 KB

  const int tid = threadIdx.x;
  const int wave = tid >> 6, lane = tid & 63;
  const int wrow = wave >> 2, wcol = wave & 3;        // 2 x 4 waves
  const int l15 = lane & 15, lk = lane >> 4;
  const int swz = (l15 & 7) << 4;                     // read-side byte xor
  const int ko0 = ((lk * 16) ^ swz) >> 1;             // ksub 0 (elements)
  const int ko1 = ((64 + lk * 16) ^ swz) >> 1;        // ksub 1
  const int sRow = lane >> 3;                         // staging src row 0..7
  const int sCol = ((lane & 7) ^ (lane >> 3)) << 3;   // inverse-swizzled col

  constexpr int NWG = (MM / BM) * (NN / BN);          // 768, %8==0
  const int b = blockIdx.x;
  const int bs = (b & 7) * (NWG >> 3) + (b >> 3);
  const int tileM = (bs / (NN / BN)) * BM;
  const int tileN = (bs % (NN / BN)) * BN;

  const u16* Agb = Ag + (size_t)tileM * KK;
  const u16* Bgb = Bg + (size_t)tileN * KK;

  f32x4 acc[8][4] = {};
  s16x8 a0[4][2], a1[4][2], bl[2][2], bh[2][2];

  auto STAGE = [&](const u16* __restrict__ G, int rowHalf, u16* ldsHalf, int kc) {
#pragma unroll
    for (int j = 0; j < 2; ++j) {
      const int c = wave * 2 + j;                     // chunk 0..15
      gload_lds16(G + (size_t)(rowHalf + c * 8 + sRow) * KK + kc + sCol,
                  ldsHalf + c * 512);
    }
  };
  auto LDA = [&](s16x8 (&af)[4][2], const u16* At, int mh) {
#pragma unroll
    for (int i = 0; i < 4; ++i) {
      const int row = wrow * 128 + (mh * 4 + i) * 16 + l15;
      const u16* p = At + row * 64;
      af[i][0] = *(const s16x8*)(p + ko0);
      af[i][1] = *(const s16x8*)(p + ko1);
    }
  };
  auto LDB = [&](s16x8 (&bf)[2][2], const u16* Bt, int nh) {
#pragma unroll
    for (int i = 0; i < 2; ++i) {
      const int row = wcol * 64 + (nh * 2 + i) * 16 + l15;
      const u16* p = Bt + row * 64;
      bf[i][0] = *(const s16x8*)(p + ko0);
      bf[i][1] = *(const s16x8*)(p + ko1);
    }
  };
  auto MFMA16 = [&](s16x8 (&af)[4][2], s16x8 (&bf)[2][2], auto MH, auto NH) {
    constexpr int mh = decltype(MH)::value, nh = decltype(NH)::value;
    __builtin_amdgcn_s_setprio(1);
#pragma unroll
    for (int k2 = 0; k2 < 2; ++k2)
#pragma unroll
      for (int i = 0; i < 4; ++i)
#pragma unroll
        for (int j = 0; j < 2; ++j)
          acc[mh * 4 + i][nh * 2 + j] = __builtin_amdgcn_mfma_f32_16x16x32_bf16(
              af[i][k2], bf[j][k2], acc[mh * 4 + i][nh * 2 + j], 0, 0, 0);
    __builtin_amdgcn_s_setprio(0);
  };
  auto BAR = [] {
    asm volatile("" ::: "memory");
    __builtin_amdgcn_s_barrier();
    asm volatile("" ::: "memory");
  };
  auto VMG = [](int n) {                               // vmcnt gate (literal)
    if (n == 6) asm volatile("s_waitcnt vmcnt(6)" ::: "memory");
    else if (n == 4) asm volatile("s_waitcnt vmcnt(4)" ::: "memory");
    else if (n == 2) asm volatile("s_waitcnt vmcnt(2)" ::: "memory");
    else if (n == 0) asm volatile("s_waitcnt vmcnt(0)" ::: "memory");
  };

  auto KT = [&](int cb, int k1, int k2, int s1, int s2, int g1, int g2, int ra) {
    // P1
    LDB(bh, sB[cb], 1);
    if (s1) STAGE(Agb, 0, sA[cb ^ 1], k1);            // A0(t+1)
    BAR();
    asm volatile("s_waitcnt lgkmcnt(4)" ::: "memory"); // readahead a0,bl done
    MFMA16(a0, bl, IC<0>{}, IC<0>{});
    VMG(g1);                                          // G1: A1(t) landed
    BAR();
    // P2
    LDA(a1, sA[cb], 1);
    if (s1) STAGE(Agb, 128, sA[cb ^ 1] + 8192, k1);   // A1(t+1)
    BAR();
    asm volatile("s_waitcnt lgkmcnt(8)" ::: "memory"); // bh done
    MFMA16(a0, bh, IC<0>{}, IC<1>{});
    BAR();
    // P3
    if (s2) STAGE(Bgb, 0, sB[cb], k2);                // B0(t+2)
    BAR();
    asm volatile("s_waitcnt lgkmcnt(0)" ::: "memory"); // a1 done
    MFMA16(a1, bh, IC<1>{}, IC<1>{});
    VMG(g2);                                          // G2: A0,B(t+1) landed
    BAR();
    // P4 (readahead is AFTER the end-P3 barrier -> cross-wave safe)
    if (s2) STAGE(Bgb, 128, sB[cb] + 8192, k2);       // B1(t+2)
    MFMA16(a1, bl, IC<1>{}, IC<0>{});
    if (ra) {                                         // tile t+1 q1 operands
      LDA(a0, sA[cb ^ 1], 0);
      LDB(bl, sB[cb ^ 1], 0);
    }
    BAR();
  };

  // Prologue: 12 loads; vmcnt(4) drains tile0 (A+B), leaves B(1); BAR makes
  // that true for ALL waves; then readahead tile0 q1; BAR (steady-state shape).
  STAGE(Bgb, 0,   sB[0], 0);
  STAGE(Bgb, 128, sB[0] + 8192, 0);
  STAGE(Agb, 0,   sA[0], 0);
  STAGE(Agb, 128, sA[0] + 8192, 0);
  STAGE(Bgb, 0,   sB[1], BK);
  STAGE(Bgb, 128, sB[1] + 8192, BK);
  asm volatile("s_waitcnt vmcnt(4)" ::: "memory");
  BAR();
  LDA(a0, sA[0], 0);
  LDB(bl, sB[0], 0);
  BAR();

#pragma unroll 1
  for (int t = 0; t < NT - 2; t += 2) {               // tiles 0..13
    KT(0, (t + 1) * BK, (t + 2) * BK, 1, 1, 6, 4, 1);
    KT(1, (t + 2) * BK, (t + 3) * BK, 1, 1, 6, 4, 1);
  }
  KT(0, (NT - 1) * BK, 0, 1, 0, 6, 2, 1);             // t=14
  KT(1, 0, 0, 0, 0, 0, -1, 0);                        // t=15

  // Epilogue: C/D layout col = lane&15, row = (lane>>4)*4 + reg
  const int r0 = tileM + wrow * 128, c0 = tileN + wcol * 64;
#pragma unroll
  for (int n = 0; n < 4; ++n) {
    const int col = c0 + n * 16 + l15;
    const float bv = bias[col];
#pragma unroll
    for (int m = 0; m < 8; ++m) {
      const int rr = r0 + m * 16 + lk * 4;
#pragma unroll
      for (int j = 0; j < 4; ++j)
        C[(size_t)(rr + j) * NN + col] = acc[m][n][j] + bv;
    }
  }
}

// ---------- fallback (ws too small): 128^2 reg-staged fp32 A ----------
__global__ __launch_bounds__(256) void gemm_fb(
    const float* __restrict__ Af, const u16* __restrict__ Bw,
    const float* __restrict__ bias, float* __restrict__ C) {
  __shared__ u16 As[128 * 64];
  __shared__ u16 Bs[128 * 64];
  const int tid = threadIdx.x;
  const int wave = tid >> 6, lane = tid & 63;
  const int l15 = lane & 15, lkq = lane >> 4;
  const int mTile = blockIdx.y * 128, nTile = blockIdx.x * 128;
  const int wr = wave >> 1, wc = wave & 1;
  f32x4 acc[4][4] = {};
  for (int k0 = 0; k0 < KK; k0 += 64) {
#pragma unroll
    for (int j = 0; j < 4; ++j) {
      const int c = wave * 4 + j;
      const int e = c * 512 + lane * 8;
      const int row = e >> 6, col = e & 63;
      gload_lds16(Bw + (size_t)(nTile + row) * KK + k0 + col, Bs + c * 512);
    }
#pragma unroll
    for (int j = 0; j < 4; ++j) {
      const int e = (j * 256 + tid) * 8;
      const int row = e >> 6, col = e & 63;
      const float* g = Af + (size_t)(mTile + row) * KK + k0 + col;
      float4 f0 = *(const float4*)g;
      float4 f1 = *(const float4*)(g + 4);
      u16x8 o;
      o[0] = f2bf(f0.x); o[1] = f2bf(f0.y); o[2] = f2bf(f0.z); o[3] = f2bf(f0.w);
      o[4] = f2bf(f1.x); o[5] = f2bf(f1.y); o[6] = f2bf(f1.z); o[7] = f2bf(f1.w);
      *(u16x8*)(As + e) = o;
    }
    __syncthreads();
    s16x8 af[4][2], bf[4][2];
#pragma unroll
    for (int m = 0; m < 4; ++m)
#pragma unroll
      for (int t = 0; t < 2; ++t)
        af[m][t] = *(const s16x8*)(As + (wr * 64 + m * 16 + l15) * 64 + t * 32 + lkq * 8);
#pragma unroll
    for (int n = 0; n < 4; ++n)
#pragma unroll
      for (int t = 0; t < 2; ++t)
        bf[n][t] = *(const s16x8*)(Bs + (wc * 64 + n * 16 + l15) * 64 + t * 32 + lkq * 8);
#pragma unroll
    for (int t = 0; t < 2; ++t)
#pragma unroll
      for (int m = 0; m < 4; ++m)
#pragma unroll
        for (int n = 0; n < 4; ++n)
          acc[m][n] = __builtin_amdgcn_mfma_f32_16x16x32_bf16(af[m][t], bf[n][t],
                                                              acc[m][n], 0, 0, 0);
    __syncthreads();
  }
  const int row0 = mTile + wr * 64, col0 = nTile + wc * 64;
#pragma unroll
  for (int n = 0; n < 4; ++n) {
    const int col = col0 + n * 16 + l15;
    const float bv = bias[col];
#pragma unroll
    for (int m = 0; m < 4; ++m) {
      const int rr = row0 + m * 16 + lkq * 4;
#pragma unroll
      for (int j = 0; j < 4; ++j)
        C[(size_t)(rr + j) * NN + col] = acc[m][n][j] + bv;
    }
  }
}

extern "C" void kernel_launch(void* const* d_in, const int* in_sizes, int n_in,
                              void* d_out, int out_size, void* d_ws, size_t ws_size,
                              hipStream_t stream) {
  const float* x     = (const float*)d_in[0];
  const float* w_qkv = (const float*)d_in[1];
  const float* b_qkv = (const float*)d_in[2];
  const float* a_q   = (const float*)d_in[3];
  const float* b_q   = (const float*)d_in[4];
  const float* a_v   = (const float*)d_in[5];
  const float* b_v   = (const float*)d_in[6];
  float* out = (float*)d_out;

  u16* weff = (u16*)d_ws;
  const size_t weff_elems = (size_t)NN * KK;
  u16* xb = weff + weff_elems;
  const size_t need = (weff_elems + (size_t)MM * KK) * sizeof(u16);

  if (ws_size >= need) {
    prep<<<dim3(WEFF_BLOCKS + CVT_BLOCKS), dim3(256), 0, stream>>>(
        w_qkv, a_q, b_q, a_v, b_v, weff, x, xb);
    gemm8p<<<dim3((MM / BM) * (NN / BN)), dim3(512), 0, stream>>>(xb, weff,
                                                                  b_qkv, out);
  } else {
    prep<<<dim3(WEFF_BLOCKS), dim3(256), 0, stream>>>(w_qkv, a_q, b_q, a_v,
                                                      b_v, weff, x, nullptr);
    gemm_fb<<<dim3(NN / 128, MM / 128), dim3(256), 0, stream>>>(x, weff,
                                                                b_qkv, out);
  }
}

// Round 7
// 220.345 us; speedup vs baseline: 1.2452x; 1.2452x over previous
//
#include <hip/hip_runtime.h>

typedef unsigned int u32;
typedef unsigned short u16;
typedef short s16x8 __attribute__((ext_vector_type(8)));
typedef u16 u16x8 __attribute__((ext_vector_type(8)));
typedef float f32x4 __attribute__((ext_vector_type(4)));
typedef __attribute__((address_space(3))) u32 as3_u32;
typedef __attribute__((address_space(1))) const u32 as1_u32;

constexpr int MM = 16384, NN = 3072, KK = 1024;
constexpr int BM = 256, BN = 256, BK = 64;
constexpr int NT = KK / BK;  // 16 K-tiles

template <int V> struct IC { static constexpr int value = V; };

__device__ __forceinline__ u16 f2bf(float f) {
  u32 u = __builtin_bit_cast(u32, f);
  u = (u + 0x7FFFu + ((u >> 16) & 1u)) >> 16;
  return (u16)u;
}

__device__ __forceinline__ void gload_lds16(const void* g, void* l) {
  __builtin_amdgcn_global_load_lds((as1_u32*)g, (as3_u32*)l, 16, 0, 0);
}

// ---------- merged prep: blocks [0,12288) fold weights, [12288,20480) cvt x ----------
constexpr int WEFF_BLOCKS = NN * KK / 256;            // 12288
constexpr int CVT_BLOCKS = MM * KK / 8 / 256;         // 8192
__global__ __launch_bounds__(256) void prep(
    const float* __restrict__ w, const float* __restrict__ aq,
    const float* __restrict__ bq, const float* __restrict__ av,
    const float* __restrict__ bv, u16* __restrict__ weff,
    const float* __restrict__ x, u16* __restrict__ xb) {
  const int bid = blockIdx.x;
  if (bid < WEFF_BLOCKS) {
    int idx = bid * 256 + threadIdx.x;
    int o = idx >> 10, d = idx & 1023;
    float val = w[idx];
    if (o < 1024) {
      float s = 0.f;
#pragma unroll
      for (int r = 0; r < 16; ++r) s += bq[o * 16 + r] * aq[r * 1024 + d];
      val += s * 0.0625f;                              // SCALING = 1/16
    } else if (o >= 2048) {
      int o2 = o - 2048;
      float s = 0.f;
#pragma unroll
      for (int r = 0; r < 16; ++r) s += bv[o2 * 16 + r] * av[r * 1024 + d];
      val += s * 0.0625f;
    }
    weff[idx] = f2bf(val);
  } else {
    size_t i = ((size_t)(bid - WEFF_BLOCKS) * 256 + threadIdx.x) * 8;
    float4 f0 = *(const float4*)(x + i);
    float4 f1 = *(const float4*)(x + i + 4);
    u16x8 o;
    o[0] = f2bf(f0.x); o[1] = f2bf(f0.y); o[2] = f2bf(f0.z); o[3] = f2bf(f0.w);
    o[4] = f2bf(f1.x); o[5] = f2bf(f1.y); o[6] = f2bf(f1.z); o[7] = f2bf(f1.w);
    *(u16x8*)(xb + i) = o;
  }
}

// ---------- 256x256 GEMM: A via LDS (swizzled, dbuf), B direct from L2 ----------
// Pipeline is uniformly 2-tiles-deep: everything tile t needs (A staged to
// sA[t&1], B frags to b{E,O} regs) is ISSUED during tile t-2 and GATED by
// vmcnt(12)+BAR at the end of tile t-1 (12 = the 12 loads issued at t-1 for
// t+1 that may remain in flight). Per-wave issue order per tile (8 B-loads,
// 4 A-stage) makes the ledger exact; in-order VMEM completion.
// Hazards: stage->sA[cb] is issued in tile t after ALL tile-t reads of
// sA[cb] are lgkm-drained (a0 drained before region-1 MFMA, a1 by explicit
// lgkm(0) before the region-2 barrier). B regs: same-parity array is
// rewritten only after its last MFMA read (compiler register WAR).
// XCD map: XCD x owns M-tiles [8x,8x+8) exclusively; within an XCD,
// consecutive blocks advance M first, N every 8 -> per-XCD working set =
// A-band 4MB (L2-resident) + ~1 B-panel (512KB) -> B gathers are L2 hits.
__global__ __launch_bounds__(512, 2) void gemm_bd(
    const u16* __restrict__ Ag, const u16* __restrict__ Bg,
    const float* __restrict__ bias, float* __restrict__ C) {
  __shared__ __align__(16) u16 sA[2][BM * BK];  // 2 x 32 KB

  const int tid = threadIdx.x;
  const int wave = tid >> 6, lane = tid & 63;
  const int wrow = wave >> 2, wcol = wave & 3;        // 2 x 4 waves
  const int l15 = lane & 15, lk = lane >> 4;
  const int swz = (l15 & 7) << 4;                     // read-side byte xor
  const int ko0 = ((lk * 16) ^ swz) >> 1;             // ksub 0 (elements)
  const int ko1 = ((64 + lk * 16) ^ swz) >> 1;        // ksub 1
  const int sRow = lane >> 3;                         // staging src row 0..7
  const int sCol = ((lane & 7) ^ (lane >> 3)) << 3;   // inverse-swizzled col

  const int b = blockIdx.x;
  const int x = b & 7, c = b >> 3;                    // 8 XCDs x 96 chunks
  const int tileM = (x * 8 + (c & 7)) * BM;           // exclusive M-band/XCD
  const int tileN = (c >> 3) * BN;                    // N advances every 8

  const u16* Agb = Ag + (size_t)tileM * KK;
  const u16* Bb = Bg + (size_t)(tileN + wcol * 64 + l15) * KK + lk * 8;

  f32x4 acc[8][4] = {};
  s16x8 a[4][2], bE[4][2], bO[4][2];

  auto STAGE_A = [&](int cb, int kc) {                // full 32KB A tile
#pragma unroll
    for (int j = 0; j < 4; ++j) {
      const int ch = wave * 4 + j;                    // chunk 0..31
      gload_lds16(Agb + (size_t)(ch * 8 + sRow) * KK + kc + sCol,
                  sA[cb] + ch * 512);
    }
  };
  auto LDBG = [&](s16x8 (&dst)[4][2], int kc) {       // 8 B-frag loads (L2)
#pragma unroll
    for (int fn = 0; fn < 4; ++fn)
#pragma unroll
      for (int k2 = 0; k2 < 2; ++k2)
        dst[fn][k2] = *(const s16x8*)(Bb + (size_t)fn * 16 * KK + kc + k2 * 32);
  };
  auto LDA = [&](int cb, int mh) {                    // 8 ds_read_b128
#pragma unroll
    for (int i = 0; i < 4; ++i) {
      const int row = wrow * 128 + (mh * 4 + i) * 16 + l15;
      const u16* p = sA[cb] + row * 64;
      a[i][0] = *(const s16x8*)(p + ko0);
      a[i][1] = *(const s16x8*)(p + ko1);
    }
  };
  auto MFMA16 = [&](s16x8 (&bf)[4][2], auto MH, auto NH) {
    constexpr int mh = decltype(MH)::value, nh = decltype(NH)::value;
    __builtin_amdgcn_s_setprio(1);
#pragma unroll
    for (int k2 = 0; k2 < 2; ++k2)
#pragma unroll
      for (int i = 0; i < 4; ++i)
#pragma unroll
        for (int j = 0; j < 2; ++j)
          acc[mh * 4 + i][nh * 2 + j] = __builtin_amdgcn_mfma_f32_16x16x32_bf16(
              a[i][k2], bf[nh * 2 + j][k2], acc[mh * 4 + i][nh * 2 + j], 0, 0, 0);
    __builtin_amdgcn_s_setprio(0);
  };
  auto BAR = [] {
    asm volatile("" ::: "memory");
    __builtin_amdgcn_s_barrier();
    asm volatile("" ::: "memory");
  };

  // tile t on buf cb; bcur = b{E,O}[t&1]; if iss: issue B(t+2)+stageA(t+2)
  // (same parity -> same LDS buf / same reg array, after their last reads).
  auto TILE = [&](int cb, s16x8 (&bcur)[4][2], int kc2, int iss, int gate) {
    // region 1: quads (0,0),(0,1)
    LDA(cb, 0);
    BAR();
    MFMA16(bcur, IC<0>{}, IC<0>{});
    MFMA16(bcur, IC<0>{}, IC<1>{});
    BAR();
    // region 2: quads (1,1),(1,0)
    LDA(cb, 1);
    asm volatile("s_waitcnt lgkmcnt(0)" ::: "memory"); // a1 drained (WAR)
    BAR();
    MFMA16(bcur, IC<1>{}, IC<1>{});
    MFMA16(bcur, IC<1>{}, IC<0>{});
    if (iss) {
      LDBG(bcur, kc2);                                // B(t+2) -> same array
      STAGE_A(cb, kc2);                               // A(t+2) -> same buf
    }
    if (gate == 12) asm volatile("s_waitcnt vmcnt(12)" ::: "memory");
    else if (gate == 0) asm volatile("s_waitcnt vmcnt(0)" ::: "memory");
    BAR();
  };

  // Prologue: [B(0) 8, A(0) 4, B(1) 8, A(1) 4] = 24; vmcnt(12) -> tile0 ready.
  LDBG(bE, 0);
  STAGE_A(0, 0);
  LDBG(bO, BK);
  STAGE_A(1, BK);
  asm volatile("s_waitcnt vmcnt(12)" ::: "memory");
  BAR();

#pragma unroll 1
  for (int t = 0; t < NT - 2; t += 2) {               // tiles 0..13 issue
    TILE(0, bE, (t + 2) * BK, 1, 12);
    TILE(1, bO, (t + 3) * BK, 1, 12);
  }
  TILE(0, bE, 0, 0, 0);                               // tile 14: drain t15
  TILE(1, bO, 0, 0, -1);                              // tile 15

  // Epilogue: C/D layout col = lane&15, row = (lane>>4)*4 + reg
  const int r0 = tileM + wrow * 128, c0 = tileN + wcol * 64;
#pragma unroll
  for (int n = 0; n < 4; ++n) {
    const int col = c0 + n * 16 + l15;
    const float bv = bias[col];
#pragma unroll
    for (int m = 0; m < 8; ++m) {
      const int rr = r0 + m * 16 + lk * 4;
#pragma unroll
      for (int j = 0; j < 4; ++j)
        C[(size_t)(rr + j) * NN + col] = acc[m][n][j] + bv;
    }
  }
}

// ---------- fallback (ws too small): 128^2 reg-staged fp32 A ----------
__global__ __launch_bounds__(256) void gemm_fb(
    const float* __restrict__ Af, const u16* __restrict__ Bw,
    const float* __restrict__ bias, float* __restrict__ C) {
  __shared__ u16 As[128 * 64];
  __shared__ u16 Bs[128 * 64];
  const int tid = threadIdx.x;
  const int wave = tid >> 6, lane = tid & 63;
  const int l15 = lane & 15, lkq = lane >> 4;
  const int mTile = blockIdx.y * 128, nTile = blockIdx.x * 128;
  const int wr = wave >> 1, wc = wave & 1;
  f32x4 acc[4][4] = {};
  for (int k0 = 0; k0 < KK; k0 += 64) {
#pragma unroll
    for (int j = 0; j < 4; ++j) {
      const int ch = wave * 4 + j;
      const int e = ch * 512 + lane * 8;
      const int row = e >> 6, col = e & 63;
      gload_lds16(Bw + (size_t)(nTile + row) * KK + k0 + col, Bs + ch * 512);
    }
#pragma unroll
    for (int j = 0; j < 4; ++j) {
      const int e = (j * 256 + tid) * 8;
      const int row = e >> 6, col = e & 63;
      const float* g = Af + (size_t)(mTile + row) * KK + k0 + col;
      float4 f0 = *(const float4*)g;
      float4 f1 = *(const float4*)(g + 4);
      u16x8 o;
      o[0] = f2bf(f0.x); o[1] = f2bf(f0.y); o[2] = f2bf(f0.z); o[3] = f2bf(f0.w);
      o[4] = f2bf(f1.x); o[5] = f2bf(f1.y); o[6] = f2bf(f1.z); o[7] = f2bf(f1.w);
      *(u16x8*)(As + e) = o;
    }
    __syncthreads();
    s16x8 af[4][2], bf[4][2];
#pragma unroll
    for (int m = 0; m < 4; ++m)
#pragma unroll
      for (int t = 0; t < 2; ++t)
        af[m][t] = *(const s16x8*)(As + (wr * 64 + m * 16 + l15) * 64 + t * 32 + lkq * 8);
#pragma unroll
    for (int n = 0; n < 4; ++n)
#pragma unroll
      for (int t = 0; t < 2; ++t)
        bf[n][t] = *(const s16x8*)(Bs + (wc * 64 + n * 16 + l15) * 64 + t * 32 + lkq * 8);
#pragma unroll
    for (int t = 0; t < 2; ++t)
#pragma unroll
      for (int m = 0; m < 4; ++m)
#pragma unroll
        for (int n = 0; n < 4; ++n)
          acc[m][n] = __builtin_amdgcn_mfma_f32_16x16x32_bf16(af[m][t], bf[n][t],
                                                              acc[m][n], 0, 0, 0);
    __syncthreads();
  }
  const int row0 = mTile + wr * 64, col0 = nTile + wc * 64;
#pragma unroll
  for (int n = 0; n < 4; ++n) {
    const int col = col0 + n * 16 + l15;
    const float bv = bias[col];
#pragma unroll
    for (int m = 0; m < 4; ++m) {
      const int rr = row0 + m * 16 + lkq * 4;
#pragma unroll
      for (int j = 0; j < 4; ++j)
        C[(size_t)(rr + j) * NN + col] = acc[m][n][j] + bv;
    }
  }
}

extern "C" void kernel_launch(void* const* d_in, const int* in_sizes, int n_in,
                              void* d_out, int out_size, void* d_ws, size_t ws_size,
                              hipStream_t stream) {
  const float* x     = (const float*)d_in[0];
  const float* w_qkv = (const float*)d_in[1];
  const float* b_qkv = (const float*)d_in[2];
  const float* a_q   = (const float*)d_in[3];
  const float* b_q   = (const float*)d_in[4];
  const float* a_v   = (const float*)d_in[5];
  const float* b_v   = (const float*)d_in[6];
  float* out = (float*)d_out;

  u16* weff = (u16*)d_ws;
  const size_t weff_elems = (size_t)NN * KK;
  u16* xb = weff + weff_elems;
  const size_t need = (weff_elems + (size_t)MM * KK) * sizeof(u16);

  if (ws_size >= need) {
    prep<<<dim3(WEFF_BLOCKS + CVT_BLOCKS), dim3(256), 0, stream>>>(
        w_qkv, a_q, b_q, a_v, b_v, weff, x, xb);
    gemm_bd<<<dim3((MM / BM) * (NN / BN)), dim3(512), 0, stream>>>(xb, weff,
                                                                   b_qkv, out);
  } else {
    prep<<<dim3(WEFF_BLOCKS), dim3(256), 0, stream>>>(w_qkv, a_q, b_q, a_v,
                                                      b_v, weff, x, nullptr);
    gemm_fb<<<dim3(NN / 128, MM / 128), dim3(256), 0, stream>>>(x, weff,
                                                                b_qkv, out);
  }
}